// Round 6
// baseline (203.717 us; speedup 1.0000x reference)
//
#include <hip/hip_runtime.h>
#include <hip/hip_bf16.h>

// LinearAttention_MLP on MI355X — round 6.
// Math: k-softmax over size-1 axis == 1 -> s = 0.125 exactly -> out = 0.125*v.
// Fold: y = x @ Weff^T, Weff = 0.125*Wo@Wv (1024x1024).
// Pipeline (3 launches; measured: wall = Sum(kernels) + ~95us fixed harness overhead):
//   weff_fused : Weff = bf16(0.125*Wo@Wv), 64x64 tiles, 256 blocks
//   main_gemm  : y_bf = bf16(x@Weff^T + b). A staged fp32 via global_load_lds
//                (async, no VGPR round-trip — round-5's reg-prefetch stalled),
//                cvt to bf16 at fragment read. XCD swizzle + XOR LDS swizzles.
//                Epilogue repacked through LDS -> dwordx4 coalesced stores.
//   rmsnorm2   : out = y/max(||y||,eps)*g*32 (fp32)
//
// Swizzle convention (round-3/5 validated):
//   STORE: LDS chunk c holds GLOBAL chunk c ^ s
//   READ : global chunk q lives at LDS chunk q ^ s

typedef __attribute__((ext_vector_type(8))) short bf16x8;
typedef __attribute__((ext_vector_type(4))) float f32x4;

struct alignas(16) bfvec8 { __hip_bfloat16 h[8]; };

__device__ __forceinline__ bfvec8 pack8(float4 a, float4 b) {
    bfvec8 o;
    o.h[0] = __float2bfloat16(a.x); o.h[1] = __float2bfloat16(a.y);
    o.h[2] = __float2bfloat16(a.z); o.h[3] = __float2bfloat16(a.w);
    o.h[4] = __float2bfloat16(b.x); o.h[5] = __float2bfloat16(b.y);
    o.h[6] = __float2bfloat16(b.z); o.h[7] = __float2bfloat16(b.w);
    return o;
}

// ---------------- weff_fused: Weff = 0.125 * Wo @ Wv, fp32 in, bf16 out ----------------
// Wo: (1024,512) row-major. Wv: (512,1024) row-major (transposed in LDS).
// 64x64 tiles, BK=32, grid 16x16 = 256 blocks.
__global__ __launch_bounds__(256)
void weff_fused(const float* __restrict__ Wo, const float* __restrict__ Wv,
                __hip_bfloat16* __restrict__ Weff) {
    __shared__ __align__(16) __hip_bfloat16 As[64 * 32];
    __shared__ __align__(16) __hip_bfloat16 Bs[64 * 32];
    __shared__ __align__(16) float Bf[32 * 65];

    const int tid  = threadIdx.x;
    const int lane = tid & 63;
    const int wave = tid >> 6;
    const int wm   = wave >> 1;
    const int wn   = wave & 1;
    const int quad = lane >> 4;
    const int tr   = lane & 15;
    const int m0   = blockIdx.y * 64;
    const int n0   = blockIdx.x * 64;

    f32x4 acc[2][2];
#pragma unroll
    for (int i = 0; i < 2; ++i)
#pragma unroll
        for (int j = 0; j < 2; ++j)
            acc[i][j] = (f32x4){0.f, 0.f, 0.f, 0.f};

    for (int kt = 0; kt < 512; kt += 32) {
        {   // A: LDS chunk c holds global chunk c ^ s
            int r = tid >> 2, c = tid & 3;
            int s = (r >> 1) & 3;
            int kg = (c ^ s) << 3;
            const float* sp = Wo + (size_t)(m0 + r) * 512 + kt + kg;
            float4 a = *(const float4*)sp, b = *(const float4*)(sp + 4);
            *(bfvec8*)(As + r * 32 + (c << 3)) = pack8(a, b);
        }
        {   // B fp32 rows (coalesced) -> Bf
            int kr = tid >> 3, c8 = (tid & 7) << 3;
            const float* sp = Wv + (size_t)(kt + kr) * 1024 + n0 + c8;
            float4 a = *(const float4*)sp, b = *(const float4*)(sp + 4);
            *(float4*)(Bf + kr * 65 + c8)     = a;
            *(float4*)(Bf + kr * 65 + c8 + 4) = b;
        }
        __syncthreads();
        {   // transpose + cvt: LDS chunk (cc ^ s) holds global chunk cc
            int n = tid >> 2, cc = tid & 3, k8 = cc << 3;
            float4 a, b;
            a.x = Bf[(k8 + 0) * 65 + n]; a.y = Bf[(k8 + 1) * 65 + n];
            a.z = Bf[(k8 + 2) * 65 + n]; a.w = Bf[(k8 + 3) * 65 + n];
            b.x = Bf[(k8 + 4) * 65 + n]; b.y = Bf[(k8 + 5) * 65 + n];
            b.z = Bf[(k8 + 6) * 65 + n]; b.w = Bf[(k8 + 7) * 65 + n];
            int cs = cc ^ ((n >> 1) & 3);
            *(bfvec8*)(Bs + n * 32 + cs * 8) = pack8(a, b);
        }
        __syncthreads();

        bf16x8 af[2], bf[2];
#pragma unroll
        for (int mi = 0; mi < 2; ++mi) {
            int r = wm * 32 + mi * 16 + tr;
            int c = quad ^ ((r >> 1) & 3);
            af[mi] = *(const bf16x8*)(As + r * 32 + c * 8);
        }
#pragma unroll
        for (int ni = 0; ni < 2; ++ni) {
            int r = wn * 32 + ni * 16 + tr;
            int c = quad ^ ((r >> 1) & 3);
            bf[ni] = *(const bf16x8*)(Bs + r * 32 + c * 8);
        }
#pragma unroll
        for (int mi = 0; mi < 2; ++mi)
#pragma unroll
            for (int ni = 0; ni < 2; ++ni)
                acc[mi][ni] = __builtin_amdgcn_mfma_f32_16x16x32_bf16(
                    af[mi], bf[ni], acc[mi][ni], 0, 0, 0);
        __syncthreads();
    }

#pragma unroll
    for (int mi = 0; mi < 2; ++mi)
#pragma unroll
        for (int ni = 0; ni < 2; ++ni) {
            const int col = n0 + wn * 32 + ni * 16 + tr;
#pragma unroll
            for (int r = 0; r < 4; ++r) {
                const int row = m0 + wm * 32 + mi * 16 + quad * 4 + r;
                Weff[(size_t)row * 1024 + col] =
                    __float2bfloat16(acc[mi][ni][r] * 0.125f);
            }
        }
}

// ---------------- main GEMM: y = x @ Weff^T + b, x fp32 staged async, bf16 out ----------------
// M=16384, N=1024, K=1024, BLK=128, BK=64. 1024 blocks.
// A: fp32 -> LDS via global_load_lds (32 KB), 16-chunk XOR swizzle (r&15),
//    bf16 cvt at fragment read. B: bf16 -> LDS (16 KB), 8-chunk XOR (r&7).
// Epilogue: acc -> LDS (stride 136 for 16B-align + bank spread) -> dwordx4 stores.
__global__ __launch_bounds__(256)
void main_gemm(const float* __restrict__ X,
               const __hip_bfloat16* __restrict__ Bt,
               const float* __restrict__ bias,
               __hip_bfloat16* __restrict__ Y) {
    __shared__ union __align__(16) {
        struct { float Af[128 * 64]; ushort Bs[128 * 64]; } s;   // 32 KB + 16 KB
        ushort Ys[128 * 136];                                     // 34 KB (epilogue)
    } sh;

    const int tid  = threadIdx.x;
    const int lane = tid & 63;
    const int wave = tid >> 6;
    const int wm   = wave >> 1;
    const int wn   = wave & 1;
    const int quad = lane >> 4;
    const int tr   = lane & 15;

    // XCD-aware mapping: all 8 n-tiles of an m-strip on one XCD (A fetched once)
    const int b   = blockIdx.x;
    const int xcd = b & 7;
    const int t   = b >> 3;
    const int nt  = t & 7;
    const int mt  = (t >> 3) * 8 + xcd;
    const int m0  = mt * 128;
    const int n0  = nt * 128;

    // B staging slots: 4 per thread. LDS chunk c (=L&7) holds global chunk c^(r&7).
    int brr[4]; size_t bofs[4];
#pragma unroll
    for (int i = 0; i < 4; ++i) {
        int L = i * 256 + tid;
        brr[i] = L >> 3;
        int c  = L & 7;
        bofs[i] = (size_t)(n0 + brr[i]) * 1024 + ((c ^ (brr[i] & 7)) << 3);
    }
    // A staging slots: 8 per thread (fp32, 16B = 4 floats per slot).
    // LDS chunk c (=L&15) holds global chunk c^(r&15).
    size_t aofs[8];
#pragma unroll
    for (int i = 0; i < 8; ++i) {
        int L = i * 256 + tid;
        int r = L >> 4;
        int c = L & 15;
        aofs[i] = (size_t)(m0 + r) * 1024 + ((c ^ (r & 15)) << 2);
    }

    f32x4 acc[4][4];
#pragma unroll
    for (int i = 0; i < 4; ++i)
#pragma unroll
        for (int j = 0; j < 4; ++j)
            acc[i][j] = (f32x4){0.f, 0.f, 0.f, 0.f};

    for (int kt = 0; kt < 1024; kt += 64) {
#pragma unroll
        for (int i = 0; i < 8; ++i) {
            int L = i * 256 + tid;
            __builtin_amdgcn_global_load_lds(
                (const __attribute__((address_space(1))) void*)(X + aofs[i] + kt),
                (__attribute__((address_space(3))) void*)(sh.s.Af + (size_t)L * 4), 16, 0, 0);
        }
#pragma unroll
        for (int i = 0; i < 4; ++i) {
            int L = i * 256 + tid;
            __builtin_amdgcn_global_load_lds(
                (const __attribute__((address_space(1))) void*)(Bt + bofs[i] + kt),
                (__attribute__((address_space(3))) void*)(sh.s.Bs + (size_t)L * 8), 16, 0, 0);
        }
        __syncthreads();

#pragma unroll
        for (int ko = 0; ko < 2; ++ko) {
            const int kb = ko * 8 + quad * 2;      // even fp32-chunk base (A)
            bf16x8 af[4], bf[4];
#pragma unroll
            for (int mi = 0; mi < 4; ++mi) {
                int r = wm * 64 + mi * 16 + tr;
                int sA = r & 15;
                const float* base = sh.s.Af + r * 64;
                float4 fa = *(const float4*)(base + ((kb ^ sA) << 2));
                float4 fb = *(const float4*)(base + (((kb + 1) ^ sA) << 2));
                bfvec8 u = pack8(fa, fb);
                af[mi] = *(bf16x8*)&u;
            }
#pragma unroll
            for (int ni = 0; ni < 4; ++ni) {
                int r = wn * 64 + ni * 16 + tr;
                int c = (ko * 4 + quad) ^ (r & 7);
                bf[ni] = *(const bf16x8*)(sh.s.Bs + (r * 8 + c) * 8);
            }
#pragma unroll
            for (int mi = 0; mi < 4; ++mi)
#pragma unroll
                for (int ni = 0; ni < 4; ++ni)
                    acc[mi][ni] = __builtin_amdgcn_mfma_f32_16x16x32_bf16(
                        af[mi], bf[ni], acc[mi][ni], 0, 0, 0);
        }
        __syncthreads();
    }
    // (final __syncthreads above guarantees all LDS reads done -> safe to alias Ys)

    // Epilogue stage 1: acc (+bias) -> Ys[rloc][cloc], stride 136 (16B-aligned rows).
#pragma unroll
    for (int mi = 0; mi < 4; ++mi)
#pragma unroll
        for (int ni = 0; ni < 4; ++ni) {
            const int cloc = wn * 64 + ni * 16 + tr;
            const float bv = bias[n0 + cloc];
#pragma unroll
            for (int r = 0; r < 4; ++r) {
                const int rloc = wm * 64 + mi * 16 + quad * 4 + r;
                __hip_bfloat16 h = __float2bfloat16(acc[mi][ni][r] + bv);
                sh.Ys[rloc * 136 + cloc] = *(ushort*)&h;
            }
        }
    __syncthreads();

    // Epilogue stage 2: coalesced read-back, 8x dwordx4 per thread.
    {
        const int row  = tid >> 1;          // 0..127
        const int half = tid & 1;           // 0..1
        const ushort* src = sh.Ys + row * 136 + half * 64;
        __hip_bfloat16* dst = Y + (size_t)(m0 + row) * 1024 + n0 + half * 64;
#pragma unroll
        for (int j = 0; j < 8; ++j) {
            uint4 w = *(const uint4*)(src + j * 8);
            *(uint4*)(dst + j * 8) = w;
        }
    }
}

// ---------------- norm: out = y / max(||y||,eps) * g * 32, 2 rows/block ----------------
__global__ __launch_bounds__(256)
void rmsnorm2(const __hip_bfloat16* __restrict__ y, const float* __restrict__ g,
              float* __restrict__ out) {
    const int wave = threadIdx.x >> 6;     // 0..3
    const int sub  = wave >> 1;            // which of 2 rows
    const int t    = threadIdx.x & 127;    // 0..127 within row
    const int row  = blockIdx.x * 2 + sub;
    const size_t base = (size_t)row * 1024 + t * 8;

    union { uint4 u; ushort s[8]; } U;
    U.u = *(const uint4*)(y + base);
    float v[8];
#pragma unroll
    for (int j = 0; j < 8; ++j)
        v[j] = __bfloat162float(*(const __hip_bfloat16*)&U.s[j]);

    float ss = 0.f;
#pragma unroll
    for (int j = 0; j < 8; ++j) ss += v[j] * v[j];
#pragma unroll
    for (int off = 32; off > 0; off >>= 1)
        ss += __shfl_down(ss, off, 64);

    __shared__ float wsum[4];
    if ((threadIdx.x & 63) == 0) wsum[wave] = ss;
    __syncthreads();
    const float total = wsum[sub * 2] + wsum[sub * 2 + 1];
    const float sc = 32.0f / fmaxf(sqrtf(total), 1e-12f);

    const float4 g0 = *(const float4*)(g + t * 8);
    const float4 g1 = *(const float4*)(g + t * 8 + 4);
    float4 o0, o1;
    o0.x = v[0] * sc * g0.x; o0.y = v[1] * sc * g0.y;
    o0.z = v[2] * sc * g0.z; o0.w = v[3] * sc * g0.w;
    o1.x = v[4] * sc * g1.x; o1.y = v[5] * sc * g1.y;
    o1.z = v[6] * sc * g1.z; o1.w = v[7] * sc * g1.w;
    *(float4*)(out + base)     = o0;
    *(float4*)(out + base + 4) = o1;
}

extern "C" void kernel_launch(void* const* d_in, const int* in_sizes, int n_in,
                              void* d_out, int out_size, void* d_ws, size_t ws_size,
                              hipStream_t stream) {
    const float* x     = (const float*)d_in[0];   // (16384, 1024)
    const float* w_qkv = (const float*)d_in[1];   // (1536, 1024)
    const float* w_out = (const float*)d_in[2];   // (1024, 512)
    const float* b_out = (const float*)d_in[3];   // (1024,)
    const float* g     = (const float*)d_in[4];   // (1, 1024)

    const int B = 16384, D = 1024, H = 512;
    const float* wv = w_qkv + (size_t)2 * H * D;  // v-rows: (512, 1024)

    char* ws = (char*)d_ws;
    size_t off = 0;
    __hip_bfloat16* weff_bf = (__hip_bfloat16*)(ws + off); off += (size_t)D * D * 2;  // 2 MB
    __hip_bfloat16* y_bf    = (__hip_bfloat16*)(ws + off); off += (size_t)B * D * 2;  // 32 MB

    weff_fused<<<dim3(D / 64, D / 64), 256, 0, stream>>>(w_out, wv, weff_bf);
    main_gemm<<<1024, 256, 0, stream>>>(x, weff_bf, b_out, y_bf);
    rmsnorm2<<<B / 2, 256, 0, stream>>>(y_bf, g, (float*)d_out);
}